// Round 1
// baseline (402.030 us; speedup 1.0000x reference)
//
#include <hip/hip_runtime.h>

// Shapes fixed by setup_inputs(): B=4, L=2048, D=768, H=12, dk=64.
// d_ws usage: Qh/Kh/Vt/attn (bf16, 12.58MB each) + masks = ~50.4 MB.

using s16x8 = __attribute__((ext_vector_type(8))) short;
using u16x4 = __attribute__((ext_vector_type(4))) unsigned short;
using f32x4 = __attribute__((ext_vector_type(4))) float;

#define MFMA16(a, b, c) __builtin_amdgcn_mfma_f32_16x16x32_bf16((a), (b), (c), 0, 0, 0)

constexpr float NEG_FILL_F = -4294967295.0f;  // -2^32 + 1
constexpr float LOG2E = 1.44269504088896340736f;

__device__ __forceinline__ unsigned short f2bf(float f) {
  union { float f; unsigned int u; } v; v.f = f;
  unsigned int u = v.u;
  return (unsigned short)((u + 0x7FFFu + ((u >> 16) & 1u)) >> 16);  // RNE
}
__device__ __forceinline__ float bf2f(unsigned short s) {
  union { unsigned int u; float f; } v; v.u = ((unsigned int)s) << 16;
  return v.f;
}

// ---------------------------------------------------------------------------
// Kernel 1: row-sum masks. mask = (sum != 0) ? 1 : 0  (sign(abs(sum)))
// ---------------------------------------------------------------------------
__global__ __launch_bounds__(256) void mask_kernel(
    const float* __restrict__ query, const float* __restrict__ key,
    float* __restrict__ qmask, float* __restrict__ kmask) {
  const float* __restrict__ src = blockIdx.y ? key : query;
  float* __restrict__ dst = blockIdx.y ? kmask : qmask;
  const int row = blockIdx.x;
  const int tid = threadIdx.x;
  float s = src[(size_t)row * 768 + tid] + src[(size_t)row * 768 + tid + 256] +
            src[(size_t)row * 768 + tid + 512];
#pragma unroll
  for (int off = 1; off < 64; off <<= 1) s += __shfl_xor(s, off);
  __shared__ float ws[4];
  if ((tid & 63) == 0) ws[tid >> 6] = s;
  __syncthreads();
  if (tid == 0) {
    float t = ws[0] + ws[1] + ws[2] + ws[3];
    dst[row] = (t != 0.0f) ? 1.0f : 0.0f;
  }
}

// ---------------------------------------------------------------------------
// Kernel 2: fused QKV projection.  out = relu(X @ W^T + b), bf16.
//   z=0: Q from query (pre-scaled by 1/8, exact in bf16) -> Qh[n][l][d]
//   z=1: K from key                                      -> Kh[n][l][d]
//   z=2: V from key, stored transposed                   -> Vt[n][d][l]
// n = h*4 + b (head-major batch, matches torch.cat(chunk) split_heads).
// 128x128 tile, BK=64, 4 waves (2x2 of 64x64), 16x16x32 bf16 MFMA.
// LDS pad 72 (stride 144B): 16B-aligned b128 reads, 2-way bank alias (free).
// ---------------------------------------------------------------------------
__global__ __launch_bounds__(256) void proj_qkv(
    const float* __restrict__ query, const float* __restrict__ key,
    const float* __restrict__ Wq, const float* __restrict__ bq,
    const float* __restrict__ Wk, const float* __restrict__ bk,
    const float* __restrict__ Wv, const float* __restrict__ bv,
    unsigned short* __restrict__ Qh, unsigned short* __restrict__ Kh,
    unsigned short* __restrict__ Vt) {
  const int z = blockIdx.z;
  const float* __restrict__ A = (z == 0) ? query : key;
  const float* __restrict__ W = (z == 0) ? Wq : (z == 1) ? Wk : Wv;
  const float* __restrict__ bias = (z == 0) ? bq : (z == 1) ? bk : bv;

  __shared__ unsigned short Al[128][72];
  __shared__ unsigned short Bl[128][72];

  const int tid = threadIdx.x;
  const int lane = tid & 63;
  const int wave = tid >> 6;
  const int wm = wave >> 1, wn = wave & 1;
  const int m0 = blockIdx.x * 128, n0 = blockIdx.y * 128;
  const int lx = lane & 15, lg = lane >> 4;

  f32x4 acc[4][4] = {};

  const int sr = tid >> 1;        // staging row 0..127
  const int sc = (tid & 1) * 32;  // staging col base (thread covers 32 of 64)

  for (int kt = 0; kt < 768; kt += 64) {
#pragma unroll
    for (int j = 0; j < 8; ++j) {
      float4 va = *(const float4*)&A[(size_t)(m0 + sr) * 768 + kt + sc + j * 4];
      u16x4 ua;
      ua[0] = f2bf(va.x); ua[1] = f2bf(va.y); ua[2] = f2bf(va.z); ua[3] = f2bf(va.w);
      *(u16x4*)&Al[sr][sc + j * 4] = ua;
      float4 vb = *(const float4*)&W[(size_t)(n0 + sr) * 768 + kt + sc + j * 4];
      u16x4 ub;
      ub[0] = f2bf(vb.x); ub[1] = f2bf(vb.y); ub[2] = f2bf(vb.z); ub[3] = f2bf(vb.w);
      *(u16x4*)&Bl[sr][sc + j * 4] = ub;
    }
    __syncthreads();
#pragma unroll
    for (int kb = 0; kb < 2; ++kb) {
      s16x8 af[4], bfr[4];
#pragma unroll
      for (int i = 0; i < 4; ++i)
        af[i] = *(const s16x8*)&Al[wm * 64 + i * 16 + lx][kb * 32 + lg * 8];
#pragma unroll
      for (int i = 0; i < 4; ++i)
        bfr[i] = *(const s16x8*)&Bl[wn * 64 + i * 16 + lx][kb * 32 + lg * 8];
#pragma unroll
      for (int i = 0; i < 4; ++i)
#pragma unroll
        for (int j = 0; j < 4; ++j)
          acc[i][j] = MFMA16(af[i], bfr[j], acc[i][j]);
    }
    __syncthreads();
  }

  // Epilogue. C-frag: col = lane&15 (feature e), row = (lane>>4)*4+r (seq m).
  const float scale = (z == 0) ? 0.125f : 1.0f;
#pragma unroll
  for (int fm = 0; fm < 4; ++fm) {
#pragma unroll
    for (int fn = 0; fn < 4; ++fn) {
      const int e = n0 + wn * 64 + fn * 16 + lx;
      const int h = e >> 6, d = e & 63;
      const int mg = m0 + wm * 64 + fm * 16 + (lg << 2);
      const int bb = mg >> 11, l = mg & 2047;
      const int n = h * 4 + bb;
      const float bv_ = bias[e];
      if (z == 2) {
        u16x4 pk;
#pragma unroll
        for (int r = 0; r < 4; ++r)
          pk[r] = f2bf(fmaxf(acc[fm][fn][r] + bv_, 0.0f));
        *(u16x4*)&Vt[((size_t)(n * 64 + d)) * 2048 + l] = pk;  // 4 consec l
      } else {
        unsigned short* dst = (z == 0) ? Qh : Kh;
#pragma unroll
        for (int r = 0; r < 4; ++r) {
          float v = fmaxf(acc[fm][fn][r] + bv_, 0.0f) * scale;
          dst[((size_t)(n * 2048 + l + r)) * 64 + d] = f2bf(v);
        }
      }
    }
  }
}

// ---------------------------------------------------------------------------
// Kernel 3: flash attention, transposed-S.
// Block: 4 waves, 128 q rows (32/wave). K-tile = 128.
// S^T = K·Q^T so C-frag col = q: softmax stats need only shfl_xor(16,32),
// O^T rescale factor is lane-uniform, P^T packs as short4 ds_write_b64.
// PV: O^T[d][q] += Vt[d][lk] · P^T[lk][q], everything K-contiguous.
// ---------------------------------------------------------------------------
__global__ __launch_bounds__(256) void attn_fwd(
    const unsigned short* __restrict__ Qh, const unsigned short* __restrict__ Kh,
    const unsigned short* __restrict__ Vt, const float* __restrict__ qmask,
    const float* __restrict__ kmask, unsigned short* __restrict__ attnw) {
  const int n = blockIdx.y;
  const int h = n >> 2, b = n & 3;
  const int q0 = blockIdx.x * 128;
  const int tid = threadIdx.x, lane = tid & 63, wave = tid >> 6;
  const int qw = q0 + wave * 32;
  const int lx = lane & 15, lg = lane >> 4;

  __shared__ unsigned short Kl[128][72];   // K tile  [lk][d]
  __shared__ unsigned short Vl[64][136];   // Vt tile [d][lk]
  __shared__ unsigned short PT[128][136];  // P^T as [q][lk] (per-wave 32 rows)
  __shared__ float kml[128];

  // Q fragments in registers for the whole kernel (B-operand of S^T MFMA).
  s16x8 qf[2][2];
#pragma unroll
  for (int fq = 0; fq < 2; ++fq)
#pragma unroll
    for (int kb = 0; kb < 2; ++kb)
      qf[fq][kb] = *(const s16x8*)&Qh[((size_t)n * 2048 + qw + fq * 16 + lx) * 64 +
                                      kb * 32 + lg * 8];

  f32x4 o[4][2] = {};  // O^T acc: [fd][fq], col=q, row=d
  float mrun[2] = {-INFINITY, -INFINITY};
  float lrun[2] = {0.0f, 0.0f};

  const int kr = tid >> 1, kc = (tid & 1) * 32;
  const int vr = tid >> 2, vc = (tid & 3) * 32;

  for (int kt = 0; kt < 2048; kt += 128) {
    {  // stage K/V tiles + key mask
      const unsigned short* sk = &Kh[((size_t)n * 2048 + kt + kr) * 64 + kc];
#pragma unroll
      for (int j = 0; j < 4; ++j)
        *(s16x8*)&Kl[kr][kc + j * 8] = *(const s16x8*)&sk[j * 8];
      const unsigned short* sv = &Vt[((size_t)n * 64 + vr) * 2048 + kt + vc];
#pragma unroll
      for (int j = 0; j < 4; ++j)
        *(s16x8*)&Vl[vr][vc + j * 8] = *(const s16x8*)&sv[j * 8];
      if (tid < 128) kml[tid] = kmask[b * 2048 + kt + tid];
    }
    __syncthreads();

    // S^T[lk][q], Q already carries the 1/8 scale.
    f32x4 s[8][2] = {};
#pragma unroll
    for (int fkr = 0; fkr < 8; ++fkr) {
      s16x8 kf0 = *(const s16x8*)&Kl[fkr * 16 + lx][lg * 8];
      s16x8 kf1 = *(const s16x8*)&Kl[fkr * 16 + lx][32 + lg * 8];
#pragma unroll
      for (int fq = 0; fq < 2; ++fq) {
        s[fkr][fq] = MFMA16(kf0, qf[fq][0], s[fkr][fq]);
        s[fkr][fq] = MFMA16(kf1, qf[fq][1], s[fkr][fq]);
      }
    }

    // key mask (rows = lk) + tile max per q
    float tmax[2] = {-INFINITY, -INFINITY};
#pragma unroll
    for (int fkr = 0; fkr < 8; ++fkr) {
#pragma unroll
      for (int r = 0; r < 4; ++r) {
        const float km = kml[fkr * 16 + lg * 4 + r];
#pragma unroll
        for (int fq = 0; fq < 2; ++fq) {
          float sv_ = s[fkr][fq][r];
          sv_ = (km != 0.0f) ? sv_ : NEG_FILL_F;
          s[fkr][fq][r] = sv_;
          tmax[fq] = fmaxf(tmax[fq], sv_);
        }
      }
    }

    float alpha[2];
#pragma unroll
    for (int fq = 0; fq < 2; ++fq) {
      tmax[fq] = fmaxf(tmax[fq], __shfl_xor(tmax[fq], 16));
      tmax[fq] = fmaxf(tmax[fq], __shfl_xor(tmax[fq], 32));
      const float mnew = fmaxf(mrun[fq], tmax[fq]);
      alpha[fq] = exp2f((mrun[fq] - mnew) * LOG2E);  // first iter: exp2(-inf)=0
      mrun[fq] = mnew;
    }

    // P = exp(s - m), write P^T to LDS (short4 = 4 consecutive lk), row sums
    float tsum[2] = {0.0f, 0.0f};
#pragma unroll
    for (int fkr = 0; fkr < 8; ++fkr) {
#pragma unroll
      for (int fq = 0; fq < 2; ++fq) {
        u16x4 pk;
#pragma unroll
        for (int r = 0; r < 4; ++r) {
          const float p = exp2f((s[fkr][fq][r] - mrun[fq]) * LOG2E);
          tsum[fq] += p;
          pk[r] = f2bf(p);
        }
        *(u16x4*)&PT[wave * 32 + fq * 16 + lx][fkr * 16 + lg * 4] = pk;
      }
    }
#pragma unroll
    for (int fq = 0; fq < 2; ++fq) {
      tsum[fq] += __shfl_xor(tsum[fq], 16);
      tsum[fq] += __shfl_xor(tsum[fq], 32);
      lrun[fq] = lrun[fq] * alpha[fq] + tsum[fq];
    }
#pragma unroll
    for (int fd = 0; fd < 4; ++fd)
#pragma unroll
      for (int fq = 0; fq < 2; ++fq)
#pragma unroll
        for (int r = 0; r < 4; ++r) o[fd][fq][r] *= alpha[fq];

    // make this wave's PT writes visible to its own cross-lane ds_reads
    asm volatile("s_waitcnt lgkmcnt(0)" ::: "memory");
    __builtin_amdgcn_sched_barrier(0);

    // PV: O^T[d][q] += Vt[d][lk] * P^T[lk][q]
#pragma unroll
    for (int kb = 0; kb < 4; ++kb) {
      s16x8 pf[2];
#pragma unroll
      for (int fq = 0; fq < 2; ++fq)
        pf[fq] = *(const s16x8*)&PT[wave * 32 + fq * 16 + lx][kb * 32 + lg * 8];
#pragma unroll
      for (int fd = 0; fd < 4; ++fd) {
        s16x8 vf = *(const s16x8*)&Vl[fd * 16 + lx][kb * 32 + lg * 8];
#pragma unroll
        for (int fq = 0; fq < 2; ++fq) o[fd][fq] = MFMA16(vf, pf[fq], o[fd][fq]);
      }
    }
    __syncthreads();
  }

  // epilogue: O / l * qmask, merged-head layout [b][q][h*64+d] (bf16)
  float osc[2];
#pragma unroll
  for (int fq = 0; fq < 2; ++fq) {
    const int qg = q0 + wave * 32 + fq * 16 + lx;
    osc[fq] = qmask[b * 2048 + qg] / lrun[fq];
  }
#pragma unroll
  for (int fd = 0; fd < 4; ++fd)
#pragma unroll
    for (int fq = 0; fq < 2; ++fq) {
      const int qg = q0 + wave * 32 + fq * 16 + lx;
      u16x4 pk;
#pragma unroll
      for (int r = 0; r < 4; ++r) pk[r] = f2bf(o[fd][fq][r] * osc[fq]);
      *(u16x4*)&attnw[((size_t)(b * 2048 + qg)) * 768 + h * 64 + fd * 16 + lg * 4] = pk;
    }
}

// ---------------------------------------------------------------------------
// Kernel 4: residual + LayerNorm (unbiased var, ddof=1) -> fp32 out
// ---------------------------------------------------------------------------
__global__ __launch_bounds__(256) void ln_kernel(
    const unsigned short* __restrict__ attnw, const float* __restrict__ query,
    const float* __restrict__ gamma, const float* __restrict__ beta,
    float* __restrict__ out) {
  const int row = blockIdx.x;
  const size_t base = (size_t)row * 768;
  const int tid = threadIdx.x;
  float x[3];
#pragma unroll
  for (int k = 0; k < 3; ++k) {
    const int i = tid + k * 256;
    x[k] = bf2f(attnw[base + i]) + query[base + i];
  }
  float s = x[0] + x[1] + x[2];
  float s2 = x[0] * x[0] + x[1] * x[1] + x[2] * x[2];
#pragma unroll
  for (int off = 1; off < 64; off <<= 1) {
    s += __shfl_xor(s, off);
    s2 += __shfl_xor(s2, off);
  }
  __shared__ float ws[4], ws2[4];
  const int wave = tid >> 6, lane = tid & 63;
  if (lane == 0) { ws[wave] = s; ws2[wave] = s2; }
  __syncthreads();
  s = ws[0] + ws[1] + ws[2] + ws[3];
  s2 = ws2[0] + ws2[1] + ws2[2] + ws2[3];
  const float mean = s * (1.0f / 768.0f);
  const float var = (s2 - 768.0f * mean * mean) * (1.0f / 767.0f);
  const float rstd = rsqrtf(var + 1e-5f);
#pragma unroll
  for (int k = 0; k < 3; ++k) {
    const int i = tid + k * 256;
    out[base + i] = gamma[i] * (x[k] - mean) * rstd + beta[i];
  }
}

// ---------------------------------------------------------------------------
extern "C" void kernel_launch(void* const* d_in, const int* in_sizes, int n_in,
                              void* d_out, int out_size, void* d_ws, size_t ws_size,
                              hipStream_t stream) {
  const float* query = (const float*)d_in[0];
  const float* key = (const float*)d_in[1];
  const float* Wq = (const float*)d_in[2];
  const float* bq = (const float*)d_in[3];
  const float* Wk = (const float*)d_in[4];
  const float* bk = (const float*)d_in[5];
  const float* Wv = (const float*)d_in[6];
  const float* bv = (const float*)d_in[7];
  const float* gamma = (const float*)d_in[8];
  const float* beta = (const float*)d_in[9];
  float* out = (float*)d_out;

  // workspace layout (bf16 tensors are 48*2048*64 = 6,291,456 elems each)
  unsigned short* Qh = (unsigned short*)d_ws;
  unsigned short* Kh = Qh + 6291456;
  unsigned short* Vt = Kh + 6291456;
  unsigned short* attnw = Vt + 6291456;
  float* qmask = (float*)(attnw + 6291456);
  float* kmask = qmask + 8192;

  mask_kernel<<<dim3(8192, 2), 256, 0, stream>>>(query, key, qmask, kmask);
  proj_qkv<<<dim3(64, 6, 3), 256, 0, stream>>>(query, key, Wq, bq, Wk, bk, Wv, bv,
                                               Qh, Kh, Vt);
  attn_fwd<<<dim3(16, 48), 256, 0, stream>>>(Qh, Kh, Vt, qmask, kmask, attnw);
  ln_kernel<<<8192, 256, 0, stream>>>(attnw, query, gamma, beta, out);
}

// Round 2
// 309.778 us; speedup vs baseline: 1.2978x; 1.2978x over previous
//
#include <hip/hip_runtime.h>

// B=4, L=2048, D=768, H=12, dk=64.  All heavy math in bf16 MFMA 16x16x32.
// ws layout (shorts): Qbf,Kbf,Qh,Kh,Vt (6291456 each), Wbf (1769472),
// attnw aliases Qbf (dead after proj). ~66.5 MB total.

using s16x8 = __attribute__((ext_vector_type(8))) short;
using u16x4 = __attribute__((ext_vector_type(4))) unsigned short;
using f32x4 = __attribute__((ext_vector_type(4))) float;

#define MFMA16(a, b, c) __builtin_amdgcn_mfma_f32_16x16x32_bf16((a), (b), (c), 0, 0, 0)

constexpr float QSCALE = 0.125f * 1.44269504088896340736f;  // 1/sqrt(64) * log2(e)
constexpr float NEG_FILL_S = -1.0e10f;                      // exp2(s+this) == 0

__device__ __forceinline__ unsigned int cvtpk(float a, float b) {
  unsigned int d;
  asm("v_cvt_pk_bf16_f32 %0, %1, %2" : "=v"(d) : "v"(a), "v"(b));
  return d;
}
__device__ __forceinline__ u16x4 pack4(float x0, float x1, float x2, float x3) {
  union { unsigned int d[2]; u16x4 v; } u;
  u.d[0] = cvtpk(x0, x1);
  u.d[1] = cvtpk(x2, x3);
  return u.v;
}
__device__ __forceinline__ unsigned short f2bf(float f) {
  union { float f; unsigned int u; } v; v.f = f;
  return (unsigned short)((v.u + 0x7FFFu + ((v.u >> 16) & 1u)) >> 16);
}
__device__ __forceinline__ float bf2f(unsigned short s) {
  union { unsigned int u; float f; } v; v.u = ((unsigned int)s) << 16;
  return v.f;
}
__device__ __forceinline__ void gll16(const void* g, void* l) {
  __builtin_amdgcn_global_load_lds(
      (const __attribute__((address_space(1))) unsigned int*)g,
      (__attribute__((address_space(3))) unsigned int*)l, 16, 0, 0);
}

// ---------------------------------------------------------------------------
// Prepass: query/key -> bf16 copies + row-sum masks (sign(abs(sum))).
// ---------------------------------------------------------------------------
__global__ __launch_bounds__(192) void prepass(
    const float* __restrict__ query, const float* __restrict__ key,
    unsigned short* __restrict__ Qbf, unsigned short* __restrict__ Kbf,
    float* __restrict__ qmask, float* __restrict__ kmask) {
  const int row = blockIdx.x, tid = threadIdx.x;
  const float* __restrict__ src = blockIdx.y ? key : query;
  unsigned short* __restrict__ dst = blockIdx.y ? Kbf : Qbf;
  float* __restrict__ msk = blockIdx.y ? kmask : qmask;
  const size_t base = (size_t)row * 768 + tid * 4;
  float4 v = *(const float4*)&src[base];
  *(u16x4*)&dst[base] = pack4(v.x, v.y, v.z, v.w);
  float s = (v.x + v.y) + (v.z + v.w);
#pragma unroll
  for (int off = 1; off < 64; off <<= 1) s += __shfl_xor(s, off);
  __shared__ float ws[3];
  if ((tid & 63) == 0) ws[tid >> 6] = s;
  __syncthreads();
  if (tid == 0) msk[row] = ((ws[0] + ws[1] + ws[2]) != 0.0f) ? 1.0f : 0.0f;
}

// ---------------------------------------------------------------------------
// Weights -> bf16 (3 x 768x768).
// ---------------------------------------------------------------------------
__global__ __launch_bounds__(256) void convw(
    const float* __restrict__ Wq, const float* __restrict__ Wk,
    const float* __restrict__ Wv, unsigned short* __restrict__ Wbf) {
  const float* __restrict__ W = (blockIdx.y == 0) ? Wq : (blockIdx.y == 1) ? Wk : Wv;
  const size_t idx = ((size_t)blockIdx.x * 256 + threadIdx.x) * 4;
  float4 v = *(const float4*)&W[idx];
  *(u16x4*)&Wbf[(size_t)blockIdx.y * 589824 + idx] = pack4(v.x, v.y, v.z, v.w);
}

// ---------------------------------------------------------------------------
// QKV projection: relu(X@W^T + b). bf16 in, bf16 out.
// 128x128 tile, BK=64, double-buffered global_load_lds with XOR-swizzled
// source (linear LDS dest, swizzled read). Q pre-scaled by QSCALE.
// z=0 -> Qh[n][l][d] (scaled), z=1 -> Kh[n][l][d], z=2 -> Vt[n][d][l].
// ---------------------------------------------------------------------------
__global__ __launch_bounds__(256, 2) void proj_qkv(
    const unsigned short* __restrict__ Qbf, const unsigned short* __restrict__ Kbf,
    const unsigned short* __restrict__ Wbf,
    const float* __restrict__ bq, const float* __restrict__ bk,
    const float* __restrict__ bv,
    unsigned short* __restrict__ Qh, unsigned short* __restrict__ Kh,
    unsigned short* __restrict__ Vt) {
  // bijective XCD swizzle over 1152 blocks (144/XCD); decode m-major, all-n.
  const int lin = blockIdx.x;
  const int swz = (lin & 7) * 144 + (lin >> 3);
  const int z = swz / 384;
  const int rem = swz - z * 384;
  const int m0 = (rem / 6) * 128, n0 = (rem % 6) * 128;
  const unsigned short* __restrict__ A = (z == 0) ? Qbf : Kbf;
  const unsigned short* __restrict__ W = Wbf + (size_t)z * 589824;
  const float* __restrict__ bias = (z == 0) ? bq : (z == 1) ? bk : bv;

  __shared__ unsigned short Al[2][128][64];
  __shared__ unsigned short Bl[2][128][64];

  const int tid = threadIdx.x, lane = tid & 63, wave = tid >> 6;
  const int wm = wave >> 1, wn = wave & 1;
  const int lx = lane & 15, lg = lane >> 4;
  const int sw = lx & 7;

  f32x4 acc[4][4] = {};

  auto stage = [&](int buf, int kt) {
#pragma unroll
    for (int i = 0; i < 4; ++i) {
      const int c = tid + i * 256;        // 16B chunk id, 1024 per tile
      const int r = c >> 3, cc = c & 7;   // dest row / dest chunk-col
      const int scol = kt + ((cc ^ (r & 7)) << 3);  // inverse-swizzled source
      gll16(&A[(size_t)(m0 + r) * 768 + scol],
            &Al[buf][0][0] + ((size_t)(i * 256 + wave * 64)) * 8);
      gll16(&W[(size_t)(n0 + r) * 768 + scol],
            &Bl[buf][0][0] + ((size_t)(i * 256 + wave * 64)) * 8);
    }
  };

  stage(0, 0);
  asm volatile("s_waitcnt vmcnt(0)" ::: "memory");
  __syncthreads();
  for (int t = 0; t < 12; ++t) {
    if (t < 11) stage((t + 1) & 1, (t + 1) * 64);
    const int buf = t & 1;
#pragma unroll
    for (int kb = 0; kb < 2; ++kb) {
      s16x8 af[4], bfr[4];
#pragma unroll
      for (int i = 0; i < 4; ++i)
        af[i] = *(const s16x8*)&Al[buf][wm * 64 + i * 16 + lx][((kb * 4 + lg) ^ sw) << 3];
#pragma unroll
      for (int i = 0; i < 4; ++i)
        bfr[i] = *(const s16x8*)&Bl[buf][wn * 64 + i * 16 + lx][((kb * 4 + lg) ^ sw) << 3];
#pragma unroll
      for (int i = 0; i < 4; ++i)
#pragma unroll
        for (int j = 0; j < 4; ++j)
          acc[i][j] = MFMA16(af[i], bfr[j], acc[i][j]);
    }
    asm volatile("s_waitcnt vmcnt(0)" ::: "memory");
    __syncthreads();
  }

  // Epilogue. C-frag: col = lane&15 (feature e), row = (lane>>4)*4+r (seq m).
  const float scale = (z == 0) ? QSCALE : 1.0f;
#pragma unroll
  for (int fm = 0; fm < 4; ++fm) {
#pragma unroll
    for (int fn = 0; fn < 4; ++fn) {
      const int e = n0 + wn * 64 + fn * 16 + lx;
      const int hh = e >> 6, d = e & 63;
      const int mg = m0 + wm * 64 + fm * 16 + (lg << 2);
      const int bb = mg >> 11, l = mg & 2047;
      const int nn = hh * 4 + bb;
      const float bv_ = bias[e];
      if (z == 2) {
        *(u16x4*)&Vt[((size_t)(nn * 64 + d)) * 2048 + l] =
            pack4(fmaxf(acc[fm][fn][0] + bv_, 0.0f), fmaxf(acc[fm][fn][1] + bv_, 0.0f),
                  fmaxf(acc[fm][fn][2] + bv_, 0.0f), fmaxf(acc[fm][fn][3] + bv_, 0.0f));
      } else {
        unsigned short* dst = (z == 0) ? Qh : Kh;
#pragma unroll
        for (int r = 0; r < 4; ++r) {
          float vv = fmaxf(acc[fm][fn][r] + bv_, 0.0f) * scale;
          dst[((size_t)(nn * 2048 + l + r)) * 64 + d] = f2bf(vv);
        }
      }
    }
  }
}

// ---------------------------------------------------------------------------
// Flash attention, transposed-S, static-max softmax (exp2 directly; scores
// carry log2e; masked keys add -1e10 before exp2 -> exact 0).
// K tile via gll+swizzle; V read straight from L2 (no block-level reuse);
// P^T in XOR-swizzled LDS [128][128]. 2 barriers/tile; K(t+1) gll issued
// after QK^T(t) so its latency hides under softmax+PV.
// ---------------------------------------------------------------------------
__global__ __launch_bounds__(256, 3) void attn_fwd(
    const unsigned short* __restrict__ Qh, const unsigned short* __restrict__ Kh,
    const unsigned short* __restrict__ Vt, const float* __restrict__ qmask,
    const float* __restrict__ kmask, unsigned short* __restrict__ attnw) {
  const int lin = blockIdx.x;                 // 768 blocks, 96/XCD
  const int swz = (lin & 7) * 96 + (lin >> 3);
  const int n = swz >> 4;
  const int q0 = (swz & 15) * 128;
  const int h = n >> 2, b = n & 3;
  const int tid = threadIdx.x, lane = tid & 63, wave = tid >> 6;
  const int lx = lane & 15, lg = lane >> 4;
  const int sw = lx & 7;

  __shared__ unsigned short Kl[128][64];   // swizzled K tile [lk][d]
  __shared__ unsigned short PT[128][128];  // swizzled P^T as [q][lk]
  __shared__ float kfill[2][128];          // additive mask fill, dbuf

  const int qw = q0 + wave * 32;
  s16x8 qf[2][2];
#pragma unroll
  for (int fq = 0; fq < 2; ++fq)
#pragma unroll
    for (int kb = 0; kb < 2; ++kb)
      qf[fq][kb] = *(const s16x8*)&Qh[((size_t)n * 2048 + qw + fq * 16 + lx) * 64 +
                                      kb * 32 + lg * 8];

  const unsigned short* __restrict__ Kbase = Kh + (size_t)n * 131072;
  const unsigned short* __restrict__ Vbase = Vt + (size_t)n * 131072;

  f32x4 o[4][2] = {};        // O^T acc: [fd][fq], col=q, row=d
  float lrun[2] = {0.0f, 0.0f};

  auto stageK = [&](int kt, int pb) {
#pragma unroll
    for (int i = 0; i < 4; ++i) {
      const int c = tid + i * 256;
      const int r = c >> 3, cc = c & 7;
      gll16(&Kbase[(size_t)(kt + r) * 64 + ((cc ^ (r & 7)) << 3)],
            &Kl[0][0] + ((size_t)(i * 256 + wave * 64)) * 8);
    }
    if (tid < 128) {
      float km = kmask[b * 2048 + kt + tid];
      kfill[pb][tid] = (km != 0.0f) ? 0.0f : NEG_FILL_S;
    }
  };

  stageK(0, 0);
  asm volatile("s_waitcnt vmcnt(0)" ::: "memory");
  __syncthreads();

  for (int t = 0; t < 16; ++t) {
    const int kt = t * 128;
    // S^T = K . Q^T  (Q carries 1/8*log2e)
    f32x4 s[8][2] = {};
#pragma unroll
    for (int fkr = 0; fkr < 8; ++fkr) {
      const int R = fkr * 16 + lx;
      s16x8 kf0 = *(const s16x8*)&Kl[R][(lg ^ sw) << 3];
      s16x8 kf1 = *(const s16x8*)&Kl[R][((4 + lg) ^ sw) << 3];
#pragma unroll
      for (int fq = 0; fq < 2; ++fq) {
        s[fkr][fq] = MFMA16(kf0, qf[fq][0], s[fkr][fq]);
        s[fkr][fq] = MFMA16(kf1, qf[fq][1], s[fkr][fq]);
      }
    }
    __syncthreads();                     // all waves done reading Kl
    if (t < 15) stageK(kt + 128, (t + 1) & 1);  // prefetch; hides under below

    // p = exp2(s + fill); accumulate l; pack P^T into swizzled LDS
#pragma unroll
    for (int fkr = 0; fkr < 8; ++fkr) {
      float4 fl = *(const float4*)&kfill[t & 1][fkr * 16 + lg * 4];
#pragma unroll
      for (int fq = 0; fq < 2; ++fq) {
        float p0 = __builtin_amdgcn_exp2f(s[fkr][fq][0] + fl.x);
        float p1 = __builtin_amdgcn_exp2f(s[fkr][fq][1] + fl.y);
        float p2 = __builtin_amdgcn_exp2f(s[fkr][fq][2] + fl.z);
        float p3 = __builtin_amdgcn_exp2f(s[fkr][fq][3] + fl.w);
        lrun[fq] += (p0 + p1) + (p2 + p3);
        const int row = wave * 32 + fq * 16 + lx;
        const int chunk = fkr * 2 + (lg >> 1);
        unsigned short* wp = &PT[row][((chunk ^ sw) << 3) + ((lg & 1) << 2)];
        uint2 pd;
        pd.x = cvtpk(p0, p1);
        pd.y = cvtpk(p2, p3);
        *(uint2*)wp = pd;
      }
    }
    asm volatile("s_waitcnt lgkmcnt(0)" ::: "memory");
    __builtin_amdgcn_sched_barrier(0);

    // PV: O^T[d][q] += V^T[d][lk] * P^T[lk][q]; V straight from global/L2
    const unsigned short* __restrict__ Vt_t = Vbase + kt;
#pragma unroll
    for (int kb = 0; kb < 4; ++kb) {
      s16x8 pf[2];
#pragma unroll
      for (int fq = 0; fq < 2; ++fq)
        pf[fq] = *(const s16x8*)&PT[wave * 32 + fq * 16 + lx][((kb * 4 + lg) ^ sw) << 3];
      s16x8 vfr[4];
#pragma unroll
      for (int fd = 0; fd < 4; ++fd)
        vfr[fd] = *(const s16x8*)&Vt_t[(size_t)(fd * 16 + lx) * 2048 + kb * 32 + lg * 8];
#pragma unroll
      for (int fd = 0; fd < 4; ++fd)
#pragma unroll
        for (int fq = 0; fq < 2; ++fq) o[fd][fq] = MFMA16(vfr[fd], pf[fq], o[fd][fq]);
    }
    asm volatile("s_waitcnt vmcnt(0)" ::: "memory");
    __syncthreads();                     // K(t+1) staged; safe to read next tile
  }

  // epilogue: l-reduce over 4-lane groups, scale by qmask/l, store bf16
#pragma unroll
  for (int fq = 0; fq < 2; ++fq) {
    lrun[fq] += __shfl_xor(lrun[fq], 16);
    lrun[fq] += __shfl_xor(lrun[fq], 32);
  }
#pragma unroll
  for (int fd = 0; fd < 4; ++fd)
#pragma unroll
    for (int fq = 0; fq < 2; ++fq) {
      const int qg = qw + fq * 16 + lx;
      const float osc = qmask[b * 2048 + qg] / lrun[fq];
      *(u16x4*)&attnw[((size_t)(b * 2048 + qg)) * 768 + h * 64 + fd * 16 + lg * 4] =
          pack4(o[fd][fq][0] * osc, o[fd][fq][1] * osc, o[fd][fq][2] * osc,
                o[fd][fq][3] * osc);
    }
}

// ---------------------------------------------------------------------------
// Residual + LayerNorm (ddof=1), vectorized: 192 threads x float4.
// ---------------------------------------------------------------------------
__global__ __launch_bounds__(192) void ln_kernel(
    const unsigned short* __restrict__ attnw, const float* __restrict__ query,
    const float* __restrict__ gamma, const float* __restrict__ beta,
    float* __restrict__ out) {
  const int row = blockIdx.x, tid = threadIdx.x;
  const size_t base = (size_t)row * 768 + tid * 4;
  u16x4 aw = *(const u16x4*)&attnw[base];
  float4 q = *(const float4*)&query[base];
  float x0 = bf2f(aw[0]) + q.x;
  float x1 = bf2f(aw[1]) + q.y;
  float x2 = bf2f(aw[2]) + q.z;
  float x3 = bf2f(aw[3]) + q.w;
  float s = (x0 + x1) + (x2 + x3);
  float s2 = (x0 * x0 + x1 * x1) + (x2 * x2 + x3 * x3);
#pragma unroll
  for (int off = 1; off < 64; off <<= 1) {
    s += __shfl_xor(s, off);
    s2 += __shfl_xor(s2, off);
  }
  __shared__ float ws[3], ws2[3];
  if ((tid & 63) == 0) { ws[tid >> 6] = s; ws2[tid >> 6] = s2; }
  __syncthreads();
  s = ws[0] + ws[1] + ws[2];
  s2 = ws2[0] + ws2[1] + ws2[2];
  const float mean = s * (1.0f / 768.0f);
  const float var = (s2 - 768.0f * mean * mean) * (1.0f / 767.0f);
  const float rstd = rsqrtf(var + 1e-5f);
  const float4 g = *(const float4*)&gamma[tid * 4];
  const float4 bt = *(const float4*)&beta[tid * 4];
  float4 r;
  r.x = g.x * (x0 - mean) * rstd + bt.x;
  r.y = g.y * (x1 - mean) * rstd + bt.y;
  r.z = g.z * (x2 - mean) * rstd + bt.z;
  r.w = g.w * (x3 - mean) * rstd + bt.w;
  *(float4*)&out[base] = r;
}

// ---------------------------------------------------------------------------
extern "C" void kernel_launch(void* const* d_in, const int* in_sizes, int n_in,
                              void* d_out, int out_size, void* d_ws, size_t ws_size,
                              hipStream_t stream) {
  const float* query = (const float*)d_in[0];
  const float* key = (const float*)d_in[1];
  const float* Wq = (const float*)d_in[2];
  const float* bq = (const float*)d_in[3];
  const float* Wk = (const float*)d_in[4];
  const float* bk = (const float*)d_in[5];
  const float* Wv = (const float*)d_in[6];
  const float* bv = (const float*)d_in[7];
  const float* gamma = (const float*)d_in[8];
  const float* beta = (const float*)d_in[9];
  float* out = (float*)d_out;

  unsigned short* Qbf = (unsigned short*)d_ws;
  unsigned short* Kbf = Qbf + 6291456;
  unsigned short* Qh = Kbf + 6291456;
  unsigned short* Kh = Qh + 6291456;
  unsigned short* Vt = Kh + 6291456;
  unsigned short* Wbf = Vt + 6291456;          // 1769472 shorts
  unsigned short* attnw = Qbf;                 // alias: Qbf dead after proj
  float* qmask = (float*)(Wbf + 1769472);
  float* kmask = qmask + 8192;

  convw<<<dim3(576, 3), 256, 0, stream>>>(Wq, Wk, Wv, Wbf);
  prepass<<<dim3(8192, 2), 192, 0, stream>>>(query, key, Qbf, Kbf, qmask, kmask);
  proj_qkv<<<1152, 256, 0, stream>>>(Qbf, Kbf, Wbf, bq, bk, bv, Qh, Kh, Vt);
  attn_fwd<<<768, 256, 0, stream>>>(Qh, Kh, Vt, qmask, kmask, attnw);
  ln_kernel<<<8192, 192, 0, stream>>>(attnw, query, gamma, beta, out);
}

// Round 3
// 229.125 us; speedup vs baseline: 1.7546x; 1.3520x over previous
//
#include <hip/hip_runtime.h>

// B=4, L=2048, D=768, H=12, dk=64.  All heavy math in bf16 MFMA 16x16x32.
// ws layout (shorts): Qbf,Kbf,Qh,Kh,Vs (6291456 each), Wbf (1769472),
// attnw aliases Qbf (dead after proj). ~66.5 MB total.
// Vs layout: [n][l/4][d][4] -> proj writes 128B-contiguous, attn reads 8B pairs.

using s16x8 = __attribute__((ext_vector_type(8))) short;
using u16x4 = __attribute__((ext_vector_type(4))) unsigned short;
using f32x4 = __attribute__((ext_vector_type(4))) float;

#define MFMA16(a, b, c) __builtin_amdgcn_mfma_f32_16x16x32_bf16((a), (b), (c), 0, 0, 0)

constexpr float QSCALE = 0.125f * 1.44269504088896340736f;  // 1/sqrt(64) * log2(e)
constexpr float NEG_FILL_S = -1.0e10f;                      // exp2(s+this) == 0

__device__ __forceinline__ unsigned int cvtpk(float a, float b) {
  unsigned int d;
  asm("v_cvt_pk_bf16_f32 %0, %1, %2" : "=v"(d) : "v"(a), "v"(b));
  return d;
}
__device__ __forceinline__ u16x4 pack4(float x0, float x1, float x2, float x3) {
  union { unsigned int d[2]; u16x4 v; } u;
  u.d[0] = cvtpk(x0, x1);
  u.d[1] = cvtpk(x2, x3);
  return u.v;
}
__device__ __forceinline__ unsigned short f2bf(float f) {
  union { float f; unsigned int u; } v; v.f = f;
  return (unsigned short)((v.u + 0x7FFFu + ((v.u >> 16) & 1u)) >> 16);
}
__device__ __forceinline__ float bf2f(unsigned short s) {
  union { unsigned int u; float f; } v; v.u = ((unsigned int)s) << 16;
  return v.f;
}
__device__ __forceinline__ void gll16(const void* g, void* l) {
  __builtin_amdgcn_global_load_lds(
      (const __attribute__((address_space(1))) unsigned int*)g,
      (__attribute__((address_space(3))) unsigned int*)l, 16, 0, 0);
}

// ---------------------------------------------------------------------------
// Prepass: query/key -> bf16 copies + row-sum masks (sign(abs(sum))).
// ---------------------------------------------------------------------------
__global__ __launch_bounds__(192) void prepass(
    const float* __restrict__ query, const float* __restrict__ key,
    unsigned short* __restrict__ Qbf, unsigned short* __restrict__ Kbf,
    float* __restrict__ qmask, float* __restrict__ kmask) {
  const int row = blockIdx.x, tid = threadIdx.x;
  const float* __restrict__ src = blockIdx.y ? key : query;
  unsigned short* __restrict__ dst = blockIdx.y ? Kbf : Qbf;
  float* __restrict__ msk = blockIdx.y ? kmask : qmask;
  const size_t base = (size_t)row * 768 + tid * 4;
  float4 v = *(const float4*)&src[base];
  *(u16x4*)&dst[base] = pack4(v.x, v.y, v.z, v.w);
  float s = (v.x + v.y) + (v.z + v.w);
#pragma unroll
  for (int off = 1; off < 64; off <<= 1) s += __shfl_xor(s, off);
  __shared__ float ws[3];
  if ((tid & 63) == 0) ws[tid >> 6] = s;
  __syncthreads();
  if (tid == 0) msk[row] = ((ws[0] + ws[1] + ws[2]) != 0.0f) ? 1.0f : 0.0f;
}

// ---------------------------------------------------------------------------
// Weights -> bf16 (3 x 768x768).
// ---------------------------------------------------------------------------
__global__ __launch_bounds__(256) void convw(
    const float* __restrict__ Wq, const float* __restrict__ Wk,
    const float* __restrict__ Wv, unsigned short* __restrict__ Wbf) {
  const float* __restrict__ W = (blockIdx.y == 0) ? Wq : (blockIdx.y == 1) ? Wk : Wv;
  const size_t idx = ((size_t)blockIdx.x * 256 + threadIdx.x) * 4;
  float4 v = *(const float4*)&W[idx];
  *(u16x4*)&Wbf[(size_t)blockIdx.y * 589824 + idx] = pack4(v.x, v.y, v.z, v.w);
}

// ---------------------------------------------------------------------------
// QKV projection: relu(X@W^T + b). bf16 in, bf16 out.
// 128x64 tile, BK=64, double-buffered global_load_lds with XOR-swizzled
// source (linear LDS dest, swizzled read). LDS 48KB -> 3 blocks/CU.
// z=0 -> Qh[n][l][d] (scaled), z=1 -> Kh[n][l][d], z=2 -> Vs[n][l/4][d][4].
// ---------------------------------------------------------------------------
__global__ __launch_bounds__(256, 3) void proj_qkv(
    const unsigned short* __restrict__ Qbf, const unsigned short* __restrict__ Kbf,
    const unsigned short* __restrict__ Wbf,
    const float* __restrict__ bq, const float* __restrict__ bk,
    const float* __restrict__ bv,
    unsigned short* __restrict__ Qh, unsigned short* __restrict__ Kh,
    unsigned short* __restrict__ Vs) {
  // bijective XCD swizzle over 1152 blocks (144/XCD).
  const int lin = blockIdx.x;
  const int swz = (lin & 7) * 144 + (lin >> 3);
  const int z = swz / 384;
  const int rem = swz - z * 384;
  const int m0 = (rem / 12) * 128, n0 = (rem % 12) * 64;
  const unsigned short* __restrict__ A = (z == 0) ? Qbf : Kbf;
  const unsigned short* __restrict__ W = Wbf + (size_t)z * 589824;
  const float* __restrict__ bias = (z == 0) ? bq : (z == 1) ? bk : bv;

  __shared__ unsigned short Al[2][128][64];
  __shared__ unsigned short Bl[2][64][64];

  const int tid = threadIdx.x, lane = tid & 63, wave = tid >> 6;
  const int wm = wave >> 1, wn = wave & 1;
  const int lx = lane & 15, lg = lane >> 4;
  const int sw = lx & 7;

  f32x4 acc[4][2] = {};

  auto stage = [&](int buf, int kt) {
#pragma unroll
    for (int i = 0; i < 4; ++i) {
      const int c = tid + i * 256;        // 16B chunk id, 1024 per A-tile
      const int r = c >> 3, cc = c & 7;
      const int scol = kt + ((cc ^ (r & 7)) << 3);
      gll16(&A[(size_t)(m0 + r) * 768 + scol],
            &Al[buf][0][0] + ((size_t)(i * 256 + wave * 64)) * 8);
    }
#pragma unroll
    for (int i = 0; i < 2; ++i) {
      const int c = tid + i * 256;        // 512 chunks per B-tile
      const int r = c >> 3, cc = c & 7;
      const int scol = kt + ((cc ^ (r & 7)) << 3);
      gll16(&W[(size_t)(n0 + r) * 768 + scol],
            &Bl[buf][0][0] + ((size_t)(i * 256 + wave * 64)) * 8);
    }
  };

  stage(0, 0);
  asm volatile("s_waitcnt vmcnt(0)" ::: "memory");
  __syncthreads();
  for (int t = 0; t < 12; ++t) {
    if (t < 11) stage((t + 1) & 1, (t + 1) * 64);
    const int buf = t & 1;
#pragma unroll
    for (int kb = 0; kb < 2; ++kb) {
      s16x8 af[4], bfr[2];
#pragma unroll
      for (int i = 0; i < 4; ++i)
        af[i] = *(const s16x8*)&Al[buf][wm * 64 + i * 16 + lx][((kb * 4 + lg) ^ sw) << 3];
#pragma unroll
      for (int j = 0; j < 2; ++j)
        bfr[j] = *(const s16x8*)&Bl[buf][wn * 32 + j * 16 + lx][((kb * 4 + lg) ^ sw) << 3];
#pragma unroll
      for (int i = 0; i < 4; ++i)
#pragma unroll
        for (int j = 0; j < 2; ++j)
          acc[i][j] = MFMA16(af[i], bfr[j], acc[i][j]);
    }
    asm volatile("s_waitcnt vmcnt(0)" ::: "memory");
    __syncthreads();
  }

  // Epilogue. C-frag: col = lane&15 (feature e), row = (lane>>4)*4+r (seq m).
  const float scale = (z == 0) ? QSCALE : 1.0f;
#pragma unroll
  for (int fm = 0; fm < 4; ++fm) {
#pragma unroll
    for (int fn = 0; fn < 2; ++fn) {
      const int e = n0 + wn * 32 + fn * 16 + lx;
      const int hh = e >> 6, d = e & 63;
      const int mg = m0 + wm * 64 + fm * 16 + (lg << 2);
      const int bb = mg >> 11, l = mg & 2047;
      const int nn = hh * 4 + bb;
      const float bv_ = bias[e];
      if (z == 2) {
        // Vs[n][l/4][d][4]: 8B per lane, 128B contiguous across lx
        *(u16x4*)&Vs[(((size_t)nn * 512 + (l >> 2)) * 64 + d) * 4] =
            pack4(fmaxf(acc[fm][fn][0] + bv_, 0.0f), fmaxf(acc[fm][fn][1] + bv_, 0.0f),
                  fmaxf(acc[fm][fn][2] + bv_, 0.0f), fmaxf(acc[fm][fn][3] + bv_, 0.0f));
      } else {
        unsigned short* dst = (z == 0) ? Qh : Kh;
#pragma unroll
        for (int r = 0; r < 4; ++r) {
          float vv = fmaxf(acc[fm][fn][r] + bv_, 0.0f) * scale;
          dst[((size_t)(nn * 2048 + l + r)) * 64 + d] = f2bf(vv);
        }
      }
    }
  }
}

// ---------------------------------------------------------------------------
// Flash attention, transposed-S, static-max softmax.
// KT=64 K-tile double-buffered via gll (1 barrier/iter); V-loads hoisted
// ahead of softmax so L2 latency hides under exp2; S stays in VGPRs.
// PT is per-wave private (rows wave*32..+32): no barrier needed around it.
// LDS = 16(Kl dbuf) + 16(PT) + 0.5 = 32.5KB.
// ---------------------------------------------------------------------------
__global__ __launch_bounds__(256, 3) void attn_fwd(
    const unsigned short* __restrict__ Qh, const unsigned short* __restrict__ Kh,
    const unsigned short* __restrict__ Vs, const float* __restrict__ qmask,
    const float* __restrict__ kmask, unsigned short* __restrict__ attnw) {
  const int lin = blockIdx.x;                 // 768 blocks, 96/XCD
  const int swz = (lin & 7) * 96 + (lin >> 3);
  const int n = swz >> 4;
  const int q0 = (swz & 15) * 128;
  const int h = n >> 2, b = n & 3;
  const int tid = threadIdx.x, lane = tid & 63, wave = tid >> 6;
  const int lx = lane & 15, lg = lane >> 4;
  const int sw = lx & 7;

  __shared__ unsigned short Kl[2][64][64];  // swizzled K tiles [lk][d], dbuf
  __shared__ unsigned short PT[128][64];    // swizzled P^T [q][lk], per-wave rows
  __shared__ float kfill[2][64];            // additive mask fill, dbuf

  const int qw = q0 + wave * 32;
  s16x8 qf[2][2];
#pragma unroll
  for (int fq = 0; fq < 2; ++fq)
#pragma unroll
    for (int kb = 0; kb < 2; ++kb)
      qf[fq][kb] = *(const s16x8*)&Qh[((size_t)n * 2048 + qw + fq * 16 + lx) * 64 +
                                      kb * 32 + lg * 8];

  const unsigned short* __restrict__ Kbase = Kh + (size_t)n * 131072;
  const unsigned short* __restrict__ Vbase = Vs + (size_t)n * 131072;

  f32x4 o[4][2] = {};        // O^T acc: [fd][fq], col=q, row=d
  float lrun[2] = {0.0f, 0.0f};

  auto stageK = [&](int kt, int buf) {
#pragma unroll
    for (int i = 0; i < 2; ++i) {
      const int c = tid + i * 256;          // 512 chunks per 64x64 tile
      const int r = c >> 3, cc = c & 7;
      gll16(&Kbase[(size_t)(kt + r) * 64 + ((cc ^ (r & 7)) << 3)],
            &Kl[buf][0][0] + ((size_t)(i * 256 + wave * 64)) * 8);
    }
    if (tid < 64) {
      float km = kmask[b * 2048 + kt + tid];
      kfill[buf][tid] = (km != 0.0f) ? 0.0f : NEG_FILL_S;
    }
  };

  stageK(0, 0);
  asm volatile("s_waitcnt vmcnt(0)" ::: "memory");
  __syncthreads();

  for (int t = 0; t < 32; ++t) {
    const int kt = t * 64;
    const int cur = t & 1;
    if (t < 31) stageK(kt + 64, cur ^ 1);   // prefetch next K tile (other buf)

    // S^T = K . Q^T  (Q carries 1/8*log2e)
    f32x4 s[4][2] = {};
#pragma unroll
    for (int fkr = 0; fkr < 4; ++fkr) {
      const int R = fkr * 16 + lx;
      s16x8 kf0 = *(const s16x8*)&Kl[cur][R][(lg ^ sw) << 3];
      s16x8 kf1 = *(const s16x8*)&Kl[cur][R][((4 + lg) ^ sw) << 3];
#pragma unroll
      for (int fq = 0; fq < 2; ++fq) {
        s[fkr][fq] = MFMA16(kf0, qf[fq][0], s[fkr][fq]);
        s[fkr][fq] = MFMA16(kf1, qf[fq][1], s[fkr][fq]);
      }
    }

    // hoist V loads: Vs[n][k/4][d][4]; per (kb,fd): pairs (g, g+1)
    uint2 vraw[8][2];
#pragma unroll
    for (int kb = 0; kb < 2; ++kb)
#pragma unroll
      for (int fd = 0; fd < 4; ++fd) {
        const int d = fd * 16 + lx;
        const int g0 = (kt >> 2) + kb * 8 + lg * 2;
        const uint2* vp = (const uint2*)&Vbase[(((size_t)g0) * 64 + d) * 4];
        vraw[kb * 4 + fd][0] = vp[0];
        vraw[kb * 4 + fd][1] = vp[64];  // g0+1: +64*4 shorts = 64 uint2
      }

    // p = exp2(s + fill); accumulate l; pack P^T into swizzled LDS
#pragma unroll
    for (int fkr = 0; fkr < 4; ++fkr) {
      float4 fl = *(const float4*)&kfill[cur][fkr * 16 + lg * 4];
#pragma unroll
      for (int fq = 0; fq < 2; ++fq) {
        float p0 = __builtin_amdgcn_exp2f(s[fkr][fq][0] + fl.x);
        float p1 = __builtin_amdgcn_exp2f(s[fkr][fq][1] + fl.y);
        float p2 = __builtin_amdgcn_exp2f(s[fkr][fq][2] + fl.z);
        float p3 = __builtin_amdgcn_exp2f(s[fkr][fq][3] + fl.w);
        lrun[fq] += (p0 + p1) + (p2 + p3);
        const int row = wave * 32 + fq * 16 + lx;
        const int chunk = fkr * 2 + (lg >> 1);
        unsigned short* wp = &PT[row][((chunk ^ sw) << 3) + ((lg & 1) << 2)];
        uint2 pd;
        pd.x = cvtpk(p0, p1);
        pd.y = cvtpk(p2, p3);
        *(uint2*)wp = pd;
      }
    }
    asm volatile("s_waitcnt lgkmcnt(0)" ::: "memory");
    __builtin_amdgcn_sched_barrier(0);

    // PV: O^T[d][q] += V^T[d][lk] * P^T[lk][q]
#pragma unroll
    for (int kb = 0; kb < 2; ++kb) {
      s16x8 pf[2];
#pragma unroll
      for (int fq = 0; fq < 2; ++fq)
        pf[fq] = *(const s16x8*)&PT[wave * 32 + fq * 16 + lx][((kb * 4 + lg) ^ sw) << 3];
#pragma unroll
      for (int fd = 0; fd < 4; ++fd) {
        union { uint2 u2[2]; s16x8 v; } vf;
        vf.u2[0] = vraw[kb * 4 + fd][0];
        vf.u2[1] = vraw[kb * 4 + fd][1];
#pragma unroll
        for (int fq = 0; fq < 2; ++fq)
          o[fd][fq] = MFMA16(vf.v, pf[fq], o[fd][fq]);
      }
    }
    asm volatile("s_waitcnt vmcnt(0)" ::: "memory");
    __syncthreads();                     // K(t+1) staged; safe to flip buffers
  }

  // epilogue: l-reduce over lg groups, scale by qmask/l, store bf16
#pragma unroll
  for (int fq = 0; fq < 2; ++fq) {
    lrun[fq] += __shfl_xor(lrun[fq], 16);
    lrun[fq] += __shfl_xor(lrun[fq], 32);
  }
#pragma unroll
  for (int fd = 0; fd < 4; ++fd)
#pragma unroll
    for (int fq = 0; fq < 2; ++fq) {
      const int qg = qw + fq * 16 + lx;
      const float osc = qmask[b * 2048 + qg] / lrun[fq];
      *(u16x4*)&attnw[((size_t)(b * 2048 + qg)) * 768 + h * 64 + fd * 16 + lg * 4] =
          pack4(o[fd][fq][0] * osc, o[fd][fq][1] * osc, o[fd][fq][2] * osc,
                o[fd][fq][3] * osc);
    }
}

// ---------------------------------------------------------------------------
// Residual + LayerNorm (ddof=1), vectorized: 192 threads x float4.
// ---------------------------------------------------------------------------
__global__ __launch_bounds__(192) void ln_kernel(
    const unsigned short* __restrict__ attnw, const float* __restrict__ query,
    const float* __restrict__ gamma, const float* __restrict__ beta,
    float* __restrict__ out) {
  const int row = blockIdx.x, tid = threadIdx.x;
  const size_t base = (size_t)row * 768 + tid * 4;
  u16x4 aw = *(const u16x4*)&attnw[base];
  float4 q = *(const float4*)&query[base];
  float x0 = bf2f(aw[0]) + q.x;
  float x1 = bf2f(aw[1]) + q.y;
  float x2 = bf2f(aw[2]) + q.z;
  float x3 = bf2f(aw[3]) + q.w;
  float s = (x0 + x1) + (x2 + x3);
  float s2 = (x0 * x0 + x1 * x1) + (x2 * x2 + x3 * x3);
#pragma unroll
  for (int off = 1; off < 64; off <<= 1) {
    s += __shfl_xor(s, off);
    s2 += __shfl_xor(s2, off);
  }
  __shared__ float ws[3], ws2[3];
  if ((tid & 63) == 0) { ws[tid >> 6] = s; ws2[tid >> 6] = s2; }
  __syncthreads();
  s = ws[0] + ws[1] + ws[2];
  s2 = ws2[0] + ws2[1] + ws2[2];
  const float mean = s * (1.0f / 768.0f);
  const float var = (s2 - 768.0f * mean * mean) * (1.0f / 767.0f);
  const float rstd = rsqrtf(var + 1e-5f);
  const float4 g = *(const float4*)&gamma[tid * 4];
  const float4 bt = *(const float4*)&beta[tid * 4];
  float4 r;
  r.x = g.x * (x0 - mean) * rstd + bt.x;
  r.y = g.y * (x1 - mean) * rstd + bt.y;
  r.z = g.z * (x2 - mean) * rstd + bt.z;
  r.w = g.w * (x3 - mean) * rstd + bt.w;
  *(float4*)&out[base] = r;
}

// ---------------------------------------------------------------------------
extern "C" void kernel_launch(void* const* d_in, const int* in_sizes, int n_in,
                              void* d_out, int out_size, void* d_ws, size_t ws_size,
                              hipStream_t stream) {
  const float* query = (const float*)d_in[0];
  const float* key = (const float*)d_in[1];
  const float* Wq = (const float*)d_in[2];
  const float* bq = (const float*)d_in[3];
  const float* Wk = (const float*)d_in[4];
  const float* bk = (const float*)d_in[5];
  const float* Wv = (const float*)d_in[6];
  const float* bv = (const float*)d_in[7];
  const float* gamma = (const float*)d_in[8];
  const float* beta = (const float*)d_in[9];
  float* out = (float*)d_out;

  unsigned short* Qbf = (unsigned short*)d_ws;
  unsigned short* Kbf = Qbf + 6291456;
  unsigned short* Qh = Kbf + 6291456;
  unsigned short* Kh = Qh + 6291456;
  unsigned short* Vs = Kh + 6291456;
  unsigned short* Wbf = Vs + 6291456;          // 1769472 shorts
  unsigned short* attnw = Qbf;                 // alias: Qbf dead after proj
  float* qmask = (float*)(Wbf + 1769472);
  float* kmask = qmask + 8192;

  convw<<<dim3(576, 3), 256, 0, stream>>>(Wq, Wk, Wv, Wbf);
  prepass<<<dim3(8192, 2), 192, 0, stream>>>(query, key, Qbf, Kbf, qmask, kmask);
  proj_qkv<<<1152, 256, 0, stream>>>(Qbf, Kbf, Wbf, bq, bk, bv, Qh, Kh, Vs);
  attn_fwd<<<768, 256, 0, stream>>>(Qh, Kh, Vs, qmask, kmask, attnw);
  ln_kernel<<<8192, 192, 0, stream>>>(attnw, query, gamma, beta, out);
}